// Round 3
// baseline (170.136 us; speedup 1.0000x reference)
//
#include <hip/hip_runtime.h>
#include <stdint.h>

// Problem constants (B,C,D,H,W) = (2,1,128,256,256)
#define BB 2
#define DD 128
#define HH 256
#define WW 256
static constexpr int64_t N = (int64_t)BB * DD * HH * WW;   // 16,777,216
static constexpr int WPR    = WW / 64;                     // 4 words per row
static constexpr int NROWS  = BB * DD * HH;                // 65,536 rows
static constexpr int K1_BLOCKS = 2048;                     // 8 blocks/CU
static constexpr int NWAVES = K1_BLOCKS * 4;               // 8192 waves
static constexpr int ROWS_PER_WAVE = NROWS / NWAVES;       // 8
static constexpr int K2_BLOCKS = (HH / 16) * (DD / 16) * (BB * WPR); // 1024
static constexpr int P0_PER_K2 = NWAVES / K2_BLOCKS;       // 8

// ---------------------------------------------------------------------------
// K1: deep-MLP streaming pass. Each wave owns 8 rows (2 batches of 4); a
// batch issues 8 independent float4 loads before any use, so every wave
// keeps ~8 cache lines' worth of loads in flight (vs 2-4 before — R2
// showed the kernel at 42us even fully cache-resident, i.e. pipeline-depth
// bound, not traffic bound). Predicate+X-dilation via wave64 __ballot +
// uniform 64-bit SALU (no cross-lane on the mask path). Per-wave partial
// of sum|t-i| goes straight to p0[wave]: no LDS, no syncthreads.
// Mask layout: word c of a row has bit l = voxel 4l+c.
// ---------------------------------------------------------------------------
__global__ __launch_bounds__(256) void mask_xdil_sum(const float* __restrict__ tgt,
                                                     const float* __restrict__ inp,
                                                     uint64_t* __restrict__ mask,
                                                     double* __restrict__ p0,
                                                     double* __restrict__ acc,
                                                     unsigned* __restrict__ counter) {
    const int lane = threadIdx.x & 63;
    const int wg   = (blockIdx.x << 2) | (threadIdx.x >> 6);   // 0..8191

    if (blockIdx.x == 0 && threadIdx.x == 0) { *acc = 0.0; *counter = 0u; }

    float s = 0.0f;
    #pragma unroll
    for (int h = 0; h < 2; ++h) {
        float4 t[4], a[4];
        #pragma unroll
        for (int k = 0; k < 4; ++k) {                 // 8 loads issued back-to-back
            const int row = wg + (h * 4 + k) * NWAVES;
            t[k] = ((const float4*)(tgt + (int64_t)row * WW))[lane];
            a[k] = ((const float4*)(inp + (int64_t)row * WW))[lane];
        }
        #pragma unroll
        for (int k = 0; k < 4; ++k) {
            const int row = wg + (h * 4 + k) * NWAVES;
            s += fabsf(t[k].x - a[k].x) + fabsf(t[k].y - a[k].y)
               + fabsf(t[k].z - a[k].z) + fabsf(t[k].w - a[k].w);

            const uint64_t b0 = __ballot(t[k].x > 0.0f && t[k].x < 1.0f);
            const uint64_t b1 = __ballot(t[k].y > 0.0f && t[k].y < 1.0f);
            const uint64_t b2 = __ballot(t[k].z > 0.0f && t[k].z < 1.0f);
            const uint64_t b3 = __ballot(t[k].w > 0.0f && t[k].w < 1.0f);

            const uint64_t U  = b0 | b1 | b2 | b3;
            const uint64_t d0 = U | ((b1 | b2 | b3) << 1);
            const uint64_t d1 = U | ((b2 | b3) << 1) | (b0 >> 1);
            const uint64_t d2 = U | (b3 << 1) | ((b0 | b1) >> 1);
            const uint64_t d3 = U | ((b0 | b1 | b2) >> 1);

            const uint64_t dv = (lane & 2) ? ((lane & 1) ? d3 : d2)
                                           : ((lane & 1) ? d1 : d0);
            if (lane < 4)
                mask[(int64_t)row * WPR + lane] = dv;   // 32B coalesced per wave
        }
    }

    #pragma unroll
    for (int off = 32; off > 0; off >>= 1)
        s += __shfl_down(s, off, 64);
    if (lane == 0) p0[wg] = (double)s;
}

// ---------------------------------------------------------------------------
// K2: fused Y+Z dilation (radius 3 each) + residual reduction + FINALIZE.
// Block = 16x16 (y,z) words for fixed (b,wx). Raw 22x22 halo -> y-dilate ->
// z-dilate into register word v. loss*N = 11*S0 - 10*SA. If v == all-ones
// (overwhelmingly common) a thread issues ZERO data loads; otherwise it
// fetches only the voxels of zero bits (voxel = 4*bit + wx). Each block
// folds its 8-double slice of p0 plus its residual into one atomicAdd;
// the last block (ticket) writes out. No third kernel launch.
// ---------------------------------------------------------------------------
__global__ __launch_bounds__(256) void yz_dil_reduce(const uint64_t* __restrict__ in,
                                                     const float* __restrict__ inp,
                                                     const float* __restrict__ tgt,
                                                     const double* __restrict__ p0,
                                                     double* __restrict__ acc,
                                                     unsigned* __restrict__ counter,
                                                     float* __restrict__ out) {
    __shared__ uint64_t raw[22][23];   // +1 pad
    __shared__ uint64_t yd[22][17];    // +1 pad
    const int ty = threadIdx.x & 15;
    const int tz = threadIdx.x >> 4;
    const int y0 = blockIdx.x * 16;
    const int z0 = blockIdx.y * 16;
    const int b  = blockIdx.z >> 2;
    const int wx = blockIdx.z & 3;

    for (int idx = threadIdx.x; idx < 22 * 22; idx += 256) {
        const int zz = idx / 22, yy = idx % 22;
        const int gz = z0 - 3 + zz, gy = y0 - 3 + yy;
        uint64_t v = 0;
        if (gz >= 0 && gz < DD && gy >= 0 && gy < HH)
            v = in[(((int64_t)(b * DD + gz)) * HH + gy) * WPR + wx];
        raw[zz][yy] = v;
    }
    __syncthreads();

    for (int idx = threadIdx.x; idx < 22 * 16; idx += 256) {
        const int zz = idx >> 4, yy = idx & 15;
        uint64_t v = 0;
        #pragma unroll
        for (int d = 0; d < 7; d++) v |= raw[zz][yy + d];
        yd[zz][yy] = v;
    }
    __syncthreads();

    uint64_t v = 0;
    #pragma unroll
    for (int d = 0; d < 7; d++) v |= yd[tz + d][ty];

    // residual: |t-i| at voxels whose dilated mask bit is 0 (rare/never)
    float sab = 0.0f;
    if (v != ~0ull) {
        uint64_t z = ~v;
        const int64_t vox = (((int64_t)(b * DD + z0 + tz)) * HH + y0 + ty) * WW + wx;
        while (z) {
            const int l = __ffsll((unsigned long long)z) - 1;
            z &= z - 1;
            const int64_t o = vox + 4 * (int64_t)l;   // voxel = 4*bit + wx
            sab += fabsf(tgt[o] - inp[o]);
        }
    }

    #pragma unroll
    for (int off = 32; off > 0; off >>= 1)
        sab += __shfl_down(sab, off, 64);
    __shared__ float ws[4];
    const int lane = threadIdx.x & 63;
    const int wv   = threadIdx.x >> 6;
    if (lane == 0) ws[wv] = sab;
    __syncthreads();

    if (threadIdx.x == 0) {
        const int flat = blockIdx.x + gridDim.x * (blockIdx.y + gridDim.y * blockIdx.z);
        double s0 = 0.0;
        #pragma unroll
        for (int k = 0; k < P0_PER_K2; ++k) s0 += p0[flat * P0_PER_K2 + k];
        const double sa = (double)((ws[0] + ws[1]) + (ws[2] + ws[3]));
        atomicAdd(acc, 11.0 * s0 - 10.0 * sa);
        __threadfence();
        const unsigned ticket = atomicAdd(counter, 1u);
        if (ticket == (unsigned)(K2_BLOCKS - 1)) {
            const double total = atomicAdd(acc, 0.0);   // atomic read: all adds visible
            out[0] = (float)(total / (double)N);
        }
    }
}

extern "C" void kernel_launch(void* const* d_in, const int* in_sizes, int n_in,
                              void* d_out, int out_size, void* d_ws, size_t ws_size,
                              hipStream_t stream) {
    const float* inp = (const float*)d_in[0];   // "input"
    const float* tgt = (const float*)d_in[1];   // "target"
    float* out = (float*)d_out;

    // workspace layout (every region fully written each run; no poison reads)
    double*   p0      = (double*)d_ws;                          // 8192 doubles = 64 KB
    double*   acc     = (double*)((char*)d_ws + 96 * 1024);     // 1 double
    unsigned* counter = (unsigned*)((char*)d_ws + 96 * 1024 + 64);
    uint64_t* mask0   = (uint64_t*)((char*)d_ws + 256 * 1024);  // 2 MB

    mask_xdil_sum<<<K1_BLOCKS, 256, 0, stream>>>(tgt, inp, mask0, p0, acc, counter);
    yz_dil_reduce<<<dim3(HH / 16, DD / 16, BB * WPR), 256, 0, stream>>>(
        mask0, inp, tgt, p0, acc, counter, out);
}